// Round 15
// baseline (100.976 us; speedup 1.0000x reference)
//
#include <hip/hip_runtime.h>
#include <math.h>

#define OUT_H 7
#define OUT_W 7
#define NBINS 49
#define REPS 3   // DIAGNOSTIC (R11 technique): 3 permuted passes in one
                 // dispatch -> kernel exceeds the ~44us top-5 profile cutoff
                 // and we get WARM counters for the R13 (scalarized) body.
                 // Each rep processes a permuted roi set; every (n,c) output
                 // is written exactly REPS times with the same correct value.
#define RFL(x) __builtin_amdgcn_readfirstlane(x)

// R13's validated body (best: 21.5us cold, absmax 0) wrapped in REPS.
// All uniform math forced scalar (RFL); loads saddr-form, shared vaddr;
// statically unrolled with scalar index clamping (dup rows harmless under
// max); one vmcnt exposure per batch; wave-private LDS, no barriers.
// Bin bounds: exact integer floor(k*roi/7) == (k*roi)/7.
// Grid bx = n*64+cg: XCD = cg%8 -> fixed 2MB channel subset per XCD L2.
__global__ __launch_bounds__(256) void roipool_v15(
    const float* __restrict__ feat, const int* __restrict__ rois,
    float* __restrict__ out)
{
    constexpr int C = 256, H = 64, W = 64, HW = H * W;
    __shared__ float racc_lds[4][OUT_H][65];   // per-wave slice, +1 pad

    const int bx   = blockIdx.x;
    const int n0   = bx >> 6;              // roi (128)
    const int cg   = bx & 63;              // channel group
    const int tid  = threadIdx.x;
    const int lane = tid & 63;             // == x
    const int wave = RFL(tid >> 6);
    const int c    = cg * 4 + wave;        // scalar

    for (int rep = 0; rep < REPS; ++rep) {
        const int n = (n0 + rep * 37) & 127;   // uniform roi permutation

        const int* r = rois + n * 5;
        const int b  = RFL(r[0]);
        const int x1 = RFL(r[1]);
        const int y1 = RFL(r[2]);
        const int roi_w = RFL(r[3]) - x1 + 1;  // scalar
        const int roi_h = RFL(r[4]) - y1 + 1;  // scalar

        const float* plane = feat + (size_t)(b * C + c) * HW;  // scalar base

        int hb[OUT_H + 1];                     // scalar bin bounds
#pragma unroll
        for (int k = 0; k <= OUT_H; ++k) hb[k] = RFL((k * roi_h) / OUT_H);

        float racc[OUT_H];
#pragma unroll
        for (int ph = 0; ph < OUT_H; ++ph) {
            const int rb = (y1 + hb[ph]) * W;            // scalar row offsets
            int rl = (y1 + hb[ph + 1] - 1) * W;          // last row of bin
            rl = rl > rb ? rl : rb;                      // empty-bin guard
            int r1 = rb + 1 * W; r1 = r1 < rl ? r1 : rl; // scalar clamps
            int r2 = rb + 2 * W; r2 = r2 < rl ? r2 : rl;
            int r3 = rb + 3 * W; r3 = r3 < rl ? r3 : rl;
            const float v0 = plane[rb + lane];           // saddr loads,
            const float v1 = plane[r1 + lane];           // shared vaddr
            const float v2 = plane[r2 + lane];
            const float v3 = plane[r3 + lane];
            racc[ph] = fmaxf(fmaxf(v0, v1), fmaxf(v2, v3));
        }
        // Tall bins (h>4; h <= ceil(48/7)=7): 3 extra rows, scalar branch.
#pragma unroll
        for (int ph = 0; ph < OUT_H; ++ph) {
            const int h = hb[ph + 1] - hb[ph];           // scalar
            if (h > 4) {
                const int rb = (y1 + hb[ph]) * W;
                const int rl = (y1 + hb[ph + 1] - 1) * W;
                int r4 = rb + 4 * W; r4 = r4 < rl ? r4 : rl;
                int r5 = rb + 5 * W; r5 = r5 < rl ? r5 : rl;
                int r6 = rb + 6 * W; r6 = r6 < rl ? r6 : rl;
                const float v4 = plane[r4 + lane];
                const float v5 = plane[r5 + lane];
                const float v6 = plane[r6 + lane];
                racc[ph] = fmaxf(racc[ph], fmaxf(v4, fmaxf(v5, v6)));
            }
        }

        // Wave-private LDS round-trip (same-wave ordering: no barrier).
#pragma unroll
        for (int ph = 0; ph < OUT_H; ++ph) racc_lds[wave][ph][lane] = racc[ph];

        if (lane < NBINS) {
            const int ph = lane / OUT_W;
            const int pw = lane - ph * OUT_W;

            const int hsL = (ph * roi_h) / OUT_H;
            const int heL = ((ph + 1) * roi_h) / OUT_H;
            const int ws  = (pw * roi_w) / OUT_W;
            const int we  = ((pw + 1) * roi_w) / OUT_W;

            const int xs = x1 + ws;
            int xl = x1 + we - 1;
            xl = xl > xs ? xl : xs;              // empty-bin guard

            float g[8];                          // max bin width 7 <= 8
#pragma unroll
            for (int j = 0; j < 8; ++j) {
                int x = xs + j;
                x = x < xl ? x : xl;             // clamp: duplicates harmless
                g[j] = racc_lds[wave][ph][x];
            }
            float m = fmaxf(fmaxf(fmaxf(g[0], g[1]), fmaxf(g[2], g[3])),
                            fmaxf(fmaxf(g[4], g[5]), fmaxf(g[6], g[7])));

            const bool valid = (heL > hsL) && (we > ws);
            out[(size_t)(n * C + c) * NBINS + lane] = valid ? m : 0.0f;
        }
        // no barrier between reps: racc_lds slice is wave-private.
    }
}

extern "C" void kernel_launch(void* const* d_in, const int* in_sizes, int n_in,
                              void* d_out, int out_size, void* d_ws, size_t ws_size,
                              hipStream_t stream) {
    const float* feat = (const float*)d_in[0];
    const int*   rois = (const int*)d_in[1];
    float*       out  = (float*)d_out;

    const int N = in_sizes[1] / 5;     // 128 rois
    const int n_blocks = N * 64;       // 4 waves/block, 1 wave per (n,c)

    roipool_v15<<<n_blocks, 256, 0, stream>>>(feat, rois, out);
}

// Round 16
// 81.635 us; speedup vs baseline: 1.2369x; 1.2369x over previous
//
#include <hip/hip_runtime.h>
#include <math.h>

#define OUT_H 7
#define OUT_W 7
#define NBINS 49
#define RFL(x) __builtin_amdgcn_readfirstlane(x)

// R15 warm counters: time tracks VMEM-instruction count (~8-9 cyc/inst TA
// service), NOT VALU (scalarization changed VALU 2x with no time change).
// v16: halve VMEM insts via dwordx2 at SCALAR row bases — one load = rows
// (r, r+1): lanes 0-31 = row r, lanes 32-63 = row r+1, same cols, zero
// per-load VALU (saddr + shared vaddr = lane*8). Pair starts are scalar:
// min(yb+2k, yl-1); overlap dups harmless under max. h==1 bins mask the
// out-of-bin half with -inf (scalar-selected lane mask); row-63 pairs shift
// down and mask the low half (also avoids OOB reads past the plane).
// Both halves land in a 2-slab LDS (ds_write_b64); phase 2 (validated since
// R4, absmax 0) takes fmax(slab0, slab1). No arrays, no barriers.
// Bin bounds: exact integer floor(k*roi/7) == (k*roi)/7.
// Grid bx = n*64+cg: XCD = cg%8 -> fixed 2MB channel subset per XCD L2.
__global__ __launch_bounds__(256) void roipool_v16(
    const float* __restrict__ feat, const int* __restrict__ rois,
    float* __restrict__ out)
{
    constexpr int C = 256, H = 64, W = 64, HW = H * W;
    // [wave][half][ph][col]: half 0 = even lanes' rows, half 1 = odd rows
    __shared__ float slab[4][2][OUT_H][W];   // 14336 B/block

    const int bx   = blockIdx.x;
    const int n    = bx >> 6;              // roi (128)
    const int cg   = bx & 63;              // channel group
    const int tid  = threadIdx.x;
    const int lane = tid & 63;
    const int wave = RFL(tid >> 6);
    const int c    = cg * 4 + wave;        // scalar

    const int* r = rois + n * 5;
    const int b  = RFL(r[0]);
    const int x1 = RFL(r[1]);
    const int y1 = RFL(r[2]);
    const int roi_w = RFL(r[3]) - x1 + 1;  // scalar
    const int roi_h = RFL(r[4]) - y1 + 1;  // scalar

    const float* plane = feat + (size_t)(b * C + c) * HW;   // scalar base
    const bool hi_half = (lane >= 32);

    int hb[OUT_H + 1];                     // scalar bin bounds
#pragma unroll
    for (int k = 0; k <= OUT_H; ++k) hb[k] = RFL((k * roi_h) / OUT_H);

    float2 racc[OUT_H];

    // ---- First pair per bin (rows yb, yb+1), with h<=1 special cases ----
#pragma unroll
    for (int ph = 0; ph < OUT_H; ++ph) {
        const int h  = hb[ph + 1] - hb[ph];          // scalar
        const int yb = y1 + hb[ph];                  // scalar
        int s0 = yb;
        if (h <= 1) s0 = yb <= 62 ? yb : 62;         // keep pair in-plane
        const bool hi_bad = (h == 1) && (yb <= 62);  // row yb+1 out-of-bin
        const bool lo_bad = (h == 1) && (yb == 63);  // shifted: row 62 bad
        const float2 v = ((const float2*)(plane + s0 * W))[lane];
        const bool kill = hi_half ? hi_bad : lo_bad;
        racc[ph].x = kill ? -INFINITY : v.x;
        racc[ph].y = kill ? -INFINITY : v.y;
    }
    // ---- Extra pairs, scalar-gated; all rows in-bin for h>=2 (dups ok) ----
#pragma unroll
    for (int ph = 0; ph < OUT_H; ++ph) {
        const int h = hb[ph + 1] - hb[ph];
        if (h > 2) {
            const int yb = y1 + hb[ph];
            const int yl = yb + h - 1;
            int s = yb + 2; s = s < yl - 1 ? s : yl - 1;
            const float2 v = ((const float2*)(plane + s * W))[lane];
            racc[ph].x = fmaxf(racc[ph].x, v.x);
            racc[ph].y = fmaxf(racc[ph].y, v.y);
        }
    }
#pragma unroll
    for (int ph = 0; ph < OUT_H; ++ph) {
        const int h = hb[ph + 1] - hb[ph];
        if (h > 4) {
            const int yb = y1 + hb[ph];
            const int yl = yb + h - 1;
            int s = yb + 4; s = s < yl - 1 ? s : yl - 1;
            const float2 v = ((const float2*)(plane + s * W))[lane];
            racc[ph].x = fmaxf(racc[ph].x, v.x);
            racc[ph].y = fmaxf(racc[ph].y, v.y);
        }
    }
#pragma unroll
    for (int ph = 0; ph < OUT_H; ++ph) {
        const int h = hb[ph + 1] - hb[ph];
        if (h > 6) {
            const int yb = y1 + hb[ph];
            const int yl = yb + h - 1;
            int s = yb + 6; s = s < yl - 1 ? s : yl - 1;
            const float2 v = ((const float2*)(plane + s * W))[lane];
            racc[ph].x = fmaxf(racc[ph].x, v.x);
            racc[ph].y = fmaxf(racc[ph].y, v.y);
        }
    }

    // ---- Stage both halves to LDS (wave-private, same-wave ordering) ----
    const int half = lane >> 5;
    const int lx2  = (lane & 31) * 2;
#pragma unroll
    for (int ph = 0; ph < OUT_H; ++ph) {
        *(float2*)&slab[wave][half][ph][lx2] = racc[ph];   // ds_write_b64
    }

    // ---- Phase 2 (validated since R4): fold halves during the gather ----
    if (lane < NBINS) {
        const int ph = lane / OUT_W;
        const int pw = lane - ph * OUT_W;

        const int hsL = (ph * roi_h) / OUT_H;
        const int heL = ((ph + 1) * roi_h) / OUT_H;
        const int ws  = (pw * roi_w) / OUT_W;
        const int we  = ((pw + 1) * roi_w) / OUT_W;

        const int xs = x1 + ws;
        int xl = x1 + we - 1;
        xl = xl > xs ? xl : xs;              // empty-bin guard

        float g[8];                          // max bin width 7 <= 8
#pragma unroll
        for (int j = 0; j < 8; ++j) {
            int x = xs + j;
            x = x < xl ? x : xl;             // clamp: duplicates harmless
            g[j] = fmaxf(slab[wave][0][ph][x], slab[wave][1][ph][x]);
        }
        float m = fmaxf(fmaxf(fmaxf(g[0], g[1]), fmaxf(g[2], g[3])),
                        fmaxf(fmaxf(g[4], g[5]), fmaxf(g[6], g[7])));

        const bool valid = (heL > hsL) && (we > ws);
        // out[n][c][ph][pw]: 49 contiguous floats per wave
        out[(size_t)(n * C + c) * NBINS + lane] = valid ? m : 0.0f;
    }
}

extern "C" void kernel_launch(void* const* d_in, const int* in_sizes, int n_in,
                              void* d_out, int out_size, void* d_ws, size_t ws_size,
                              hipStream_t stream) {
    const float* feat = (const float*)d_in[0];
    const int*   rois = (const int*)d_in[1];
    float*       out  = (float*)d_out;

    const int N = in_sizes[1] / 5;     // 128 rois
    const int n_blocks = N * 64;       // 4 waves/block, 1 wave per (n,c)

    roipool_v16<<<n_blocks, 256, 0, stream>>>(feat, rois, out);
}

// Round 17
// 80.915 us; speedup vs baseline: 1.2479x; 1.0089x over previous
//
#include <hip/hip_runtime.h>
#include <math.h>

#define OUT_H 7
#define OUT_W 7
#define NBINS 49
#define PADW 66   // slab row stride: even (keeps ds_write_b64 8B-aligned) and
                  // != 0 mod 32 per ph (gather bank = (2ph+x)%32 -> spread).
                  // R16 used stride 64 -> 7-way aligned conflicts in phase 2
                  // = the entire regression. This is the one-line fix.
#define RFL(x) __builtin_amdgcn_readfirstlane(x)

// v17 = R16 (dwordx2 scalar-row-pair loads, VMEM insts 35 -> ~17) with LDS
// padding restored. One dwordx2 load at a scalar row base = rows (r, r+1):
// lanes 0-31 = row r, lanes 32-63 = row r+1, same cols; saddr + shared
// vaddr = lane*8 -> zero per-load VALU. Pair starts scalar: min(yb+2k, yl-1);
// overlap dups harmless under max. h==1 bins mask the out-of-bin half with
// -inf; row-63 pairs shift down and mask the low half (no OOB reads).
// Both halves land in 2 padded LDS slabs (ds_write_b64); phase 2 (validated
// since R4, absmax 0) folds the halves during the gather. No barriers.
// Bin bounds: exact integer floor(k*roi/7) == (k*roi)/7.
// Grid bx = n*64+cg: XCD = cg%8 -> fixed 2MB channel subset per XCD L2.
__global__ __launch_bounds__(256) void roipool_v17(
    const float* __restrict__ feat, const int* __restrict__ rois,
    float* __restrict__ out)
{
    constexpr int C = 256, H = 64, W = 64, HW = H * W;
    // [wave][half][ph][col(padded)]
    __shared__ float slab[4][2][OUT_H][PADW];   // 14784 B/block

    const int bx   = blockIdx.x;
    const int n    = bx >> 6;              // roi (128)
    const int cg   = bx & 63;              // channel group
    const int tid  = threadIdx.x;
    const int lane = tid & 63;
    const int wave = RFL(tid >> 6);
    const int c    = cg * 4 + wave;        // scalar

    const int* r = rois + n * 5;
    const int b  = RFL(r[0]);
    const int x1 = RFL(r[1]);
    const int y1 = RFL(r[2]);
    const int roi_w = RFL(r[3]) - x1 + 1;  // scalar
    const int roi_h = RFL(r[4]) - y1 + 1;  // scalar

    const float* plane = feat + (size_t)(b * C + c) * HW;   // scalar base
    const bool hi_half = (lane >= 32);

    int hb[OUT_H + 1];                     // scalar bin bounds
#pragma unroll
    for (int k = 0; k <= OUT_H; ++k) hb[k] = RFL((k * roi_h) / OUT_H);

    float2 racc[OUT_H];

    // ---- First pair per bin (rows yb, yb+1), with h<=1 special cases ----
#pragma unroll
    for (int ph = 0; ph < OUT_H; ++ph) {
        const int h  = hb[ph + 1] - hb[ph];          // scalar
        const int yb = y1 + hb[ph];                  // scalar
        int s0 = yb;
        if (h <= 1) s0 = yb <= 62 ? yb : 62;         // keep pair in-plane
        const bool hi_bad = (h == 1) && (yb <= 62);  // row yb+1 out-of-bin
        const bool lo_bad = (h == 1) && (yb == 63);  // shifted: row 62 bad
        const float2 v = ((const float2*)(plane + s0 * W))[lane];
        const bool kill = hi_half ? hi_bad : lo_bad;
        racc[ph].x = kill ? -INFINITY : v.x;
        racc[ph].y = kill ? -INFINITY : v.y;
    }
    // ---- Extra pairs, scalar-gated; all rows in-bin for h>=2 (dups ok) ----
#pragma unroll
    for (int ph = 0; ph < OUT_H; ++ph) {
        const int h = hb[ph + 1] - hb[ph];
        if (h > 2) {
            const int yb = y1 + hb[ph];
            const int yl = yb + h - 1;
            int s = yb + 2; s = s < yl - 1 ? s : yl - 1;
            const float2 v = ((const float2*)(plane + s * W))[lane];
            racc[ph].x = fmaxf(racc[ph].x, v.x);
            racc[ph].y = fmaxf(racc[ph].y, v.y);
        }
    }
#pragma unroll
    for (int ph = 0; ph < OUT_H; ++ph) {
        const int h = hb[ph + 1] - hb[ph];
        if (h > 4) {
            const int yb = y1 + hb[ph];
            const int yl = yb + h - 1;
            int s = yb + 4; s = s < yl - 1 ? s : yl - 1;
            const float2 v = ((const float2*)(plane + s * W))[lane];
            racc[ph].x = fmaxf(racc[ph].x, v.x);
            racc[ph].y = fmaxf(racc[ph].y, v.y);
        }
    }
#pragma unroll
    for (int ph = 0; ph < OUT_H; ++ph) {
        const int h = hb[ph + 1] - hb[ph];
        if (h > 6) {
            const int yb = y1 + hb[ph];
            const int yl = yb + h - 1;
            int s = yb + 6; s = s < yl - 1 ? s : yl - 1;
            const float2 v = ((const float2*)(plane + s * W))[lane];
            racc[ph].x = fmaxf(racc[ph].x, v.x);
            racc[ph].y = fmaxf(racc[ph].y, v.y);
        }
    }

    // ---- Stage both halves to LDS (wave-private, same-wave ordering) ----
    const int half = lane >> 5;
    const int lx2  = (lane & 31) * 2;      // even -> 8B-aligned with PADW=66
#pragma unroll
    for (int ph = 0; ph < OUT_H; ++ph) {
        *(float2*)&slab[wave][half][ph][lx2] = racc[ph];   // ds_write_b64
    }

    // ---- Phase 2 (validated since R4): fold halves during the gather ----
    if (lane < NBINS) {
        const int ph = lane / OUT_W;
        const int pw = lane - ph * OUT_W;

        const int hsL = (ph * roi_h) / OUT_H;
        const int heL = ((ph + 1) * roi_h) / OUT_H;
        const int ws  = (pw * roi_w) / OUT_W;
        const int we  = ((pw + 1) * roi_w) / OUT_W;

        const int xs = x1 + ws;
        int xl = x1 + we - 1;
        xl = xl > xs ? xl : xs;              // empty-bin guard

        float g[8];                          // max bin width 7 <= 8
#pragma unroll
        for (int j = 0; j < 8; ++j) {
            int x = xs + j;
            x = x < xl ? x : xl;             // clamp: duplicates harmless
            g[j] = fmaxf(slab[wave][0][ph][x], slab[wave][1][ph][x]);
        }
        float m = fmaxf(fmaxf(fmaxf(g[0], g[1]), fmaxf(g[2], g[3])),
                        fmaxf(fmaxf(g[4], g[5]), fmaxf(g[6], g[7])));

        const bool valid = (heL > hsL) && (we > ws);
        // out[n][c][ph][pw]: 49 contiguous floats per wave
        out[(size_t)(n * C + c) * NBINS + lane] = valid ? m : 0.0f;
    }
}

extern "C" void kernel_launch(void* const* d_in, const int* in_sizes, int n_in,
                              void* d_out, int out_size, void* d_ws, size_t ws_size,
                              hipStream_t stream) {
    const float* feat = (const float*)d_in[0];
    const int*   rois = (const int*)d_in[1];
    float*       out  = (float*)d_out;

    const int N = in_sizes[1] / 5;     // 128 rois
    const int n_blocks = N * 64;       // 4 waves/block, 1 wave per (n,c)

    roipool_v17<<<n_blocks, 256, 0, stream>>>(feat, rois, out);
}

// Round 18
// 72.737 us; speedup vs baseline: 1.3882x; 1.1124x over previous
//
#include <hip/hip_runtime.h>
#include <math.h>

#define OUT_H 7
#define OUT_W 7
#define NBINS 49
#define PAD 66                 // dword row stride: even (all b64 LDS ops stay
                               // 8B-aligned) and 66%32=2 spreads banks per row
#define TSZ (64 * PAD)         // dwords per table

// v18 — shared-plane pyramid. R9-R17 all plateau at 21-27us because the
// per-(n,c) structure replicates window reads + bounds math 256x per roi
// (warm: VALU 62%, VMEM ~50%, LDS ~30%: nothing saturated, everything
// half-busy). v18: one block per (b,c) plane; stage plane to LDS ONCE
// (VMEM insts drop 32x), build clamped col-max tables C2,C4 (RMQ trick:
// max over w in [2^j, 2^{j+1}) cols = max of 2 reads of C_{2^j}), then all
// rois of the batch answer every bin from LDS: 2 reads x 7 clamp-unrolled
// rows. Bin bounds: exact integer floor(k*roi/7) (the reference's min-
// clamps provably never bind under exact math; absmax 0 since R4).
__global__ __launch_bounds__(256) void roipool_v18(
    const float* __restrict__ feat, const int* __restrict__ rois, int nroi,
    float* __restrict__ out)
{
    constexpr int C = 256, H = 64, W = 64, HW = H * W;
    __shared__ float tab[3 * TSZ];          // C1 | C2 | C4   (50688 B)
    __shared__ unsigned char bh[128][8];    // absolute row bounds per roi
    __shared__ unsigned char bw[128][8];    // absolute col bounds per roi
    __shared__ unsigned char lst[128];      // rois of this batch (any order)
    __shared__ int cnt;

    const int bx = blockIdx.x;
    const int b  = bx >> 8;       // batch (4)
    const int c  = bx & 255;      // channel (256)
    const int t  = threadIdx.x;

    if (t == 0) cnt = 0;
    __syncthreads();              // cnt init vs atomicAdd

    // ---- Stage plane -> C1, dense float4 loads (1KB/wave-load) ----
    const float* plane = feat + (size_t)(b * C + c) * HW;
#pragma unroll
    for (int i = 0; i < 4; ++i) {
        const int f = t + 256 * i;            // float4 index 0..1023
        const float4 v = ((const float4*)plane)[f];
        const int row = f >> 4, c4 = f & 15;
        float* dst = &tab[row * PAD + c4 * 4];
        *(float2*)dst       = make_float2(v.x, v.y);   // b64 (8B-aligned)
        *(float2*)(dst + 2) = make_float2(v.z, v.w);
    }

    // ---- Bounds (t<128: rows of roi t; t>=128: cols) + compaction ----
    {
        const int rr = t & 127;
        if (rr < nroi) {
            const int* rp = rois + rr * 5;
            if (t < 128) {
                const int y1 = rp[2];
                const int rh = rp[4] - y1 + 1;
#pragma unroll
                for (int k = 0; k <= 7; ++k)
                    bh[rr][k] = (unsigned char)(y1 + (k * rh) / OUT_H);
                if (rp[0] == b) {             // this batch: append to list
                    const int p = atomicAdd(&cnt, 1);
                    lst[p] = (unsigned char)rr;
                }
            } else {
                const int x1 = rp[1];
                const int rw = rp[3] - x1 + 1;
#pragma unroll
                for (int k = 0; k <= 7; ++k)
                    bw[rr][k] = (unsigned char)(x1 + (k * rw) / OUT_W);
            }
        }
    }
    __syncthreads();              // C1 + bounds + list ready

    // ---- Build C2 then C4 (thread owns row=t>>2, cols q*16..q*16+15) ----
    const int row = t >> 2, q = t & 3, x0 = q * 16;
    float2 w2[8];
    {
        const float* src = &tab[row * PAD + x0];
        float2 r[8];
#pragma unroll
        for (int i = 0; i < 8; ++i) r[i] = ((const float2*)src)[i];
        const float nb = tab[row * PAD + (x0 + 16 < 64 ? x0 + 16 : 63)];
#pragma unroll
        for (int i = 0; i < 8; ++i) {
            const float nx = (i < 7) ? r[i + 1].x : nb;
            w2[i].x = fmaxf(r[i].x, r[i].y);      // C2[x]   = max(x, x+1c)
            w2[i].y = fmaxf(r[i].y, nx);
        }
        float* dst = &tab[TSZ + row * PAD + x0];
#pragma unroll
        for (int i = 0; i < 8; ++i) ((float2*)dst)[i] = w2[i];
    }
    __syncthreads();              // C2 ready (cross-thread neighbor)
    {
        const float2 nb2 =
            *(const float2*)&tab[TSZ + row * PAD + (x0 + 16 < 64 ? x0 + 16 : 62)];
        const float n16 = (x0 + 16 < 64) ? nb2.x : nb2.y;  // C2[x0+16 clamp]
        const float n17 = nb2.y;                            // C2[x0+17 clamp]
        float2 u[8];
#pragma unroll
        for (int i = 0; i < 8; ++i) {
            const float d0 = (i < 7) ? w2[i + 1].x : n16;
            const float d1 = (i < 7) ? w2[i + 1].y : n17;
            u[i].x = fmaxf(w2[i].x, d0);          // C4[x] = max(C2[x], C2[x+2c])
            u[i].y = fmaxf(w2[i].y, d1);
        }
        float* dst = &tab[2 * TSZ + row * PAD + x0];
#pragma unroll
        for (int i = 0; i < 8; ++i) ((float2*)dst)[i] = u[i];
    }
    __syncthreads();              // C4 ready

    // ---- Queries: all bins of all rois of this batch, from LDS ----
    const int tot = cnt * NBINS;
    for (int g = t; g < tot; g += 256) {
        const int li  = g / NBINS;
        const int bin = g - li * NBINS;
        const int n   = lst[li];
        const int ph  = (bin * 37) >> 8;          // exact bin/7 for 0..48
        const int pw  = bin - ph * OUT_W;

        const int ys = bh[n][ph],  ye = bh[n][ph + 1];
        const int xs = bw[n][pw],  xe = bw[n][pw + 1];
        const int h = ye - ys, w = xe - xs;       // 0..7

        int toff, shf;                            // col table + 2nd-read shift
        if (w >= 4)      { toff = 2 * TSZ; shf = w - 4; }
        else if (w >= 2) { toff = TSZ;     shf = w - 2; }
        else             { toff = 0;       shf = 0;     }

        const int ylim = (h > 0) ? (ye - 1) : ys; // all reads stay in-image
        float m = -INFINITY;
#pragma unroll
        for (int j = 0; j < 7; ++j) {
            int yj = ys + j;
            yj = yj < ylim ? yj : ylim;           // dup rows harmless (max)
            const int a = toff + yj * PAD + xs;
            m = fmaxf(m, fmaxf(tab[a], tab[a + shf]));
        }
        const float res = (h > 0 && w > 0) ? m : 0.0f;
        out[(n * C + c) * NBINS + bin] = res;     // 49-contig runs per roi
    }
}

extern "C" void kernel_launch(void* const* d_in, const int* in_sizes, int n_in,
                              void* d_out, int out_size, void* d_ws, size_t ws_size,
                              hipStream_t stream) {
    const float* feat = (const float*)d_in[0];
    const int*   rois = (const int*)d_in[1];
    float*       out  = (float*)d_out;

    int nroi = in_sizes[1] / 5;        // 128
    if (nroi > 128) nroi = 128;

    roipool_v18<<<4 * 256, 256, 0, stream>>>(feat, rois, nroi, out);
}